// Round 3
// baseline (1717.037 us; speedup 1.0000x reference)
//
#include <hip/hip_runtime.h>
#include <math.h>

// ---------------------------------------------------------------------------
// GNN pool: 2x GCNConv(elu) + MLP(128) + Linear(15) + softmax
// N=100000, E=3200000, IN=3, HID=64, MLP_HID=128, K=15, all fp32.
//
// Round-3 pipeline: no CSR, no global scatter of col.
//   memset cursor -> scatter (bucket edges by dst>>7, counting sort, packed
//   (dstLow7<<17)|src in 4B) -> degsx (per-bucket LDS degree hist + dis/sx)
//   -> agg3b (per-bucket LDS-atomic 3-feat aggregate + W1 + elu -> s1)
//   -> agg64b (per-bucket 32KB LDS accumulator, lane=feature, s1 gathers
//      from LLC) -> head (fused W2/elu/Wm1/elu/Wm2/softmax, round-2 version).
//
// Rationale: round-2's fill_kernel wrote 197 MB HBM for a 12.8 MB col array
// (lone 4B scattered writes -> 16x line amplification across XCDs). Bucketing
// converts ALL dst-scattered ops into LDS-local ops; the only remaining
// scatter is the bucketed edge write, which lands in ~10-entry runs.
// ---------------------------------------------------------------------------

#define SPAN 128          // nodes per bucket
#define CAP  4608         // bucket capacity (mean 4096, sd ~64 for this E/N)
#define CH   8192         // edges per scatter chunk
#define NT   16
#define NTP  17

// ---- counting scatter: edges -> buckets by dst>>7, packed (dl<<17)|src ----
__global__ __launch_bounds__(256) void scatter_kernel(const int* __restrict__ src,
    const int* __restrict__ dst, int* __restrict__ cursor, unsigned* __restrict__ colb,
    int E, int NBK, int nChunks) {
    __shared__ int hist[1024];
    __shared__ unsigned gb[1024];
    int tid = threadIdx.x;
    for (int chunk = blockIdx.x; chunk < nChunks; chunk += gridDim.x) {
        for (int i = tid; i < NBK; i += 256) hist[i] = 0;
        __syncthreads();
        int base = chunk * CH;
        int cnt = min(CH, E - base);
        unsigned br[32], dt[32];
#pragma unroll
        for (int j = 0; j < 32; ++j) {
            int idx = j * 256 + tid;
            br[j] = 0xFFFFFFFFu;
            if (idx < cnt) {
                int e = base + idx;
                int s = src[e], d = dst[e];
                int b = d >> 7;
                int r = atomicAdd(&hist[b], 1);
                br[j] = ((unsigned)b << 13) | (unsigned)r;   // b<1024 (10b), r<8192 (13b)
                dt[j] = ((unsigned)(d & 127) << 17) | (unsigned)s;  // src < 2^17
            }
        }
        __syncthreads();
        for (int b = tid; b < NBK; b += 256) {
            int c = hist[b];
            gb[b] = (unsigned)(b * CAP) + (c ? (unsigned)atomicAdd(&cursor[b], c) : 0u);
        }
        __syncthreads();
#pragma unroll
        for (int j = 0; j < 32; ++j) {
            if (br[j] != 0xFFFFFFFFu) {
                int b = br[j] >> 13;
                int r = br[j] & 8191;
                unsigned pos = gb[b] + (unsigned)r;
                if (pos < (unsigned)(b + 1) * CAP) colb[pos] = dt[j];  // overflow guard
            }
        }
        __syncthreads();
    }
}

// ---- per-bucket degree hist + dis = rsqrt(deg+1) + sx = dis*x ----
__global__ __launch_bounds__(256) void degsx_kernel(const unsigned* __restrict__ colb,
    const int* __restrict__ cursor, const float* __restrict__ x,
    float* __restrict__ dis, float* __restrict__ sx, int N) {
    __shared__ int cnt128[SPAN];
    int b = blockIdx.x, tid = threadIdx.x;
    if (tid < SPAN) cnt128[tid] = 0;
    __syncthreads();
    int n = min(cursor[b], CAP);
    int base = b * CAP;
    for (int i = tid; i < n; i += 256) {
        unsigned e = colb[base + i];
        atomicAdd(&cnt128[(e >> 17) & 127], 1);
    }
    __syncthreads();
    if (tid < SPAN) {
        int node = b * SPAN + tid;
        if (node < N) {
            float r = rsqrtf((float)(cnt128[tid] + 1));
            dis[node] = r;
            sx[node * 3 + 0] = r * x[node * 3 + 0];
            sx[node * 3 + 1] = r * x[node * 3 + 1];
            sx[node * 3 + 2] = r * x[node * 3 + 2];
        }
    }
}

// ---- layer 1: per-bucket LDS-atomic aggregate of sx (3 feats) + W1 + elu ----
__global__ __launch_bounds__(256) void agg3b_kernel(const unsigned* __restrict__ colb,
    const int* __restrict__ cursor, const float* __restrict__ sx,
    const float* __restrict__ dis, const float* __restrict__ W1,
    const float* __restrict__ b1, float* __restrict__ s1, int N) {
    __shared__ float acc[SPAN * 4];   // [dl][c], c padded to 4
    __shared__ float W1s[192], b1s[64];
    int b = blockIdx.x, tid = threadIdx.x;
    for (int i = tid; i < SPAN * 4; i += 256) acc[i] = 0.f;
    if (tid < 192) W1s[tid] = W1[tid];
    if (tid < 64)  b1s[tid] = b1[tid];
    __syncthreads();
    int n = min(cursor[b], CAP);
    int base = b * CAP;
    for (int i = tid; i < n; i += 256) {
        unsigned e = colb[base + i];
        int s = e & 0x1FFFF, dl = (e >> 17) & 127;
        atomicAdd(&acc[dl * 4 + 0], sx[s * 3 + 0]);
        atomicAdd(&acc[dl * 4 + 1], sx[s * 3 + 1]);
        atomicAdd(&acc[dl * 4 + 2], sx[s * 3 + 2]);
    }
    __syncthreads();
    if (tid < SPAN) {   // self loop
        int node = b * SPAN + tid;
        if (node < N) {
            acc[tid * 4 + 0] += sx[node * 3 + 0];
            acc[tid * 4 + 1] += sx[node * 3 + 1];
            acc[tid * 4 + 2] += sx[node * 3 + 2];
        }
    }
    __syncthreads();
    for (int k = 0; k < SPAN * 64 / 256; ++k) {
        int o = k * 256 + tid;
        int dl = o >> 6, f = o & 63;
        int node = b * SPAN + dl;
        if (node < N) {
            float r = dis[node];
            float v = r * (acc[dl * 4] * W1s[f] + acc[dl * 4 + 1] * W1s[64 + f]
                           + acc[dl * 4 + 2] * W1s[128 + f]) + b1s[f];
            v = (v > 0.f) ? v : expm1f(v);
            s1[(size_t)node * 64 + f] = r * v;   // pre-scaled for next aggregation
        }
    }
}

// ---- layer 2: per-bucket 32KB LDS accumulator, lane=feature ----
__global__ __launch_bounds__(512) void agg64b_kernel(const unsigned* __restrict__ colb,
    const int* __restrict__ cursor, const float* __restrict__ s1,
    const float* __restrict__ dis, float* __restrict__ a2, int N) {
    __shared__ float acc[SPAN * 64];   // 32 KB
    __shared__ unsigned eb[1024];
    __shared__ float rs[SPAN];
    int b = blockIdx.x, tid = threadIdx.x;
    for (int i = tid; i < SPAN * 64; i += 512) acc[i] = 0.f;
    if (tid < SPAN) { int node = b * SPAN + tid; rs[tid] = (node < N) ? dis[node] : 0.f; }
    __syncthreads();
    int n = min(cursor[b], CAP);
    int base = b * CAP;
    int lane = tid & 63;
    int w4 = (tid >> 6) * 4;   // 8 waves x 4 edges each per group of 32
    for (int st = 0; st < n; st += 1024) {
        int m = min(1024, n - st);
        for (int i = tid; i < m; i += 512) eb[i] = colb[base + st + i];
        __syncthreads();
        for (int i0 = w4; i0 < m; i0 += 32) {
            unsigned e0 = eb[i0];
            unsigned e1 = (i0 + 1 < m) ? eb[i0 + 1] : 0u;
            unsigned e2 = (i0 + 2 < m) ? eb[i0 + 2] : 0u;
            unsigned e3 = (i0 + 3 < m) ? eb[i0 + 3] : 0u;
            float v0 = s1[(size_t)(e0 & 0x1FFFF) * 64 + lane];
            float v1 = (i0 + 1 < m) ? s1[(size_t)(e1 & 0x1FFFF) * 64 + lane] : 0.f;
            float v2 = (i0 + 2 < m) ? s1[(size_t)(e2 & 0x1FFFF) * 64 + lane] : 0.f;
            float v3 = (i0 + 3 < m) ? s1[(size_t)(e3 & 0x1FFFF) * 64 + lane] : 0.f;
            atomicAdd(&acc[((e0 >> 17) & 127) * 64 + lane], v0);
            atomicAdd(&acc[((e1 >> 17) & 127) * 64 + lane], v1);
            atomicAdd(&acc[((e2 >> 17) & 127) * 64 + lane], v2);
            atomicAdd(&acc[((e3 >> 17) & 127) * 64 + lane], v3);
        }
        __syncthreads();
    }
    for (int k = 0; k < SPAN * 64 / 512; ++k) {
        int o = k * 512 + tid;
        int dl = o >> 6, f = o & 63;
        int node = b * SPAN + dl;
        if (node < N)
            a2[(size_t)node * 64 + f] = rs[dl] * (acc[o] + s1[(size_t)node * 64 + f]);
    }
}

// ---- fused head: out = softmax(elu(elu(a2@W2+b2)@Wm1+bm1)@Wm2+bm2) ----
__global__ __launch_bounds__(256) void head_kernel(const float* __restrict__ a2,
    const float* __restrict__ W2g, const float* __restrict__ b2g,
    const float* __restrict__ Wm1g, const float* __restrict__ bm1g,
    const float* __restrict__ Wm2g, const float* __restrict__ bm2g,
    float* __restrict__ out, int N) {
    __shared__ float W2s[64 * 64];
    __shared__ float Wm1s[64 * 128];
    __shared__ float b2s[64];
    __shared__ float bm1s[128];
    __shared__ float bm2s[16];
    __shared__ float at[64 * NTP];
    __shared__ float tt[64 * NTP];
    __shared__ float mt[NT * 129];
    __shared__ float ot[NT * 16];
    int tid = threadIdx.x;
    for (int i = tid; i < 64 * 64;  i += 256) W2s[i]  = W2g[i];
    for (int i = tid; i < 64 * 128; i += 256) Wm1s[i] = Wm1g[i];
    if (tid < 64)  b2s[tid]  = b2g[tid];
    if (tid < 128) bm1s[tid] = bm1g[tid];
    if (tid < 16)  bm2s[tid] = (tid < 15) ? bm2g[tid] : 0.f;
    __syncthreads();

    int nTiles = (N + NT - 1) / NT;
    int f  = tid & 63;
    int n0 = (tid >> 6) * 4;
    int cc16 = tid & 15;
    int cn   = tid >> 4;
    int coff = (cc16 < 15) ? cc16 : 0;

    for (int tile = blockIdx.x; tile < nTiles; tile += gridDim.x) {
        int base = tile * NT;
        {
            int n = tid >> 6, k = tid & 63;
#pragma unroll
            for (int g = 0; g < 4; ++g) {
                int nn = n * 4 + g;
                int node = base + nn; if (node >= N) node = N - 1;
                at[k * NTP + nn] = a2[(size_t)node * 64 + k];
            }
        }
        __syncthreads();
        {
            float bb = b2s[f];
            float acc0 = bb, acc1 = bb, acc2 = bb, acc3 = bb;
#pragma unroll 4
            for (int k = 0; k < 64; ++k) {
                float w = W2s[k * 64 + f];
                const float* a = &at[k * NTP + n0];
                acc0 = fmaf(w, a[0], acc0);
                acc1 = fmaf(w, a[1], acc1);
                acc2 = fmaf(w, a[2], acc2);
                acc3 = fmaf(w, a[3], acc3);
            }
            float* t = &tt[f * NTP + n0];
            t[0] = (acc0 > 0.f) ? acc0 : expm1f(acc0);
            t[1] = (acc1 > 0.f) ? acc1 : expm1f(acc1);
            t[2] = (acc2 > 0.f) ? acc2 : expm1f(acc2);
            t[3] = (acc3 > 0.f) ? acc3 : expm1f(acc3);
        }
        __syncthreads();
#pragma unroll
        for (int pass = 0; pass < 2; ++pass) {
            int j = f + pass * 64;
            float bb = bm1s[j];
            float acc0 = bb, acc1 = bb, acc2 = bb, acc3 = bb;
#pragma unroll 4
            for (int ff = 0; ff < 64; ++ff) {
                float w = Wm1s[ff * 128 + j];
                const float* t = &tt[ff * NTP + n0];
                acc0 = fmaf(w, t[0], acc0);
                acc1 = fmaf(w, t[1], acc1);
                acc2 = fmaf(w, t[2], acc2);
                acc3 = fmaf(w, t[3], acc3);
            }
            mt[(n0 + 0) * 129 + j] = (acc0 > 0.f) ? acc0 : expm1f(acc0);
            mt[(n0 + 1) * 129 + j] = (acc1 > 0.f) ? acc1 : expm1f(acc1);
            mt[(n0 + 2) * 129 + j] = (acc2 > 0.f) ? acc2 : expm1f(acc2);
            mt[(n0 + 3) * 129 + j] = (acc3 > 0.f) ? acc3 : expm1f(acc3);
        }
        __syncthreads();
        {
            float acc = bm2s[cc16];
#pragma unroll 4
            for (int j = 0; j < 128; ++j) {
                acc = fmaf(mt[cn * 129 + j], Wm2g[j * 15 + coff], acc);
            }
            if (cc16 < 15) ot[cn * 16 + cc16] = acc;
        }
        __syncthreads();
        {
            int node = base + cn;
            if (cc16 < 15 && node < N) {
                float mx = -1e30f;
#pragma unroll
                for (int c2 = 0; c2 < 15; ++c2) mx = fmaxf(mx, ot[cn * 16 + c2]);
                float ssum = 0.f;
#pragma unroll
                for (int c2 = 0; c2 < 15; ++c2) ssum += __expf(ot[cn * 16 + c2] - mx);
                out[(size_t)node * 15 + cc16] = __expf(ot[cn * 16 + cc16] - mx) / ssum;
            }
        }
        __syncthreads();
    }
}

extern "C" void kernel_launch(void* const* d_in, const int* in_sizes, int n_in,
                              void* d_out, int out_size, void* d_ws, size_t ws_size,
                              hipStream_t stream) {
    const float* x   = (const float*)d_in[0];
    const int*   ei  = (const int*)d_in[1];
    const float* W1  = (const float*)d_in[2];
    const float* b1  = (const float*)d_in[3];
    const float* W2  = (const float*)d_in[4];
    const float* b2  = (const float*)d_in[5];
    const float* Wm1 = (const float*)d_in[6];
    const float* bm1 = (const float*)d_in[7];
    const float* Wm2 = (const float*)d_in[8];
    const float* bm2 = (const float*)d_in[9];
    float* out = (float*)d_out;

    int N = in_sizes[0] / 3;
    int E = in_sizes[1] / 2;
    const int* src = ei;
    const int* dst = ei + E;
    int NBK = (N + SPAN - 1) / SPAN;   // 782

    uintptr_t p = (uintptr_t)d_ws;
    auto carve = [&](size_t bytes) -> void* {
        p = (p + 255) & ~(uintptr_t)255;
        void* r = (void*)p;
        p += bytes;
        return r;
    };
    int*      cursor = (int*)carve((size_t)NBK * 4);
    unsigned* colb   = (unsigned*)carve((size_t)NBK * CAP * 4);
    float*    dis    = (float*)carve((size_t)N * 4);
    float*    sx     = (float*)carve((size_t)N * 12);
    float*    s1     = (float*)carve((size_t)N * 64 * 4);
    float*    a2     = (float*)carve((size_t)N * 64 * 4);

    hipMemsetAsync(cursor, 0, (size_t)NBK * 4, stream);

    int nChunks = (E + CH - 1) / CH;
    scatter_kernel<<<nChunks, 256, 0, stream>>>(src, dst, cursor, colb, E, NBK, nChunks);
    degsx_kernel<<<NBK, 256, 0, stream>>>(colb, cursor, x, dis, sx, N);
    agg3b_kernel<<<NBK, 256, 0, stream>>>(colb, cursor, sx, dis, W1, b1, s1, N);
    agg64b_kernel<<<NBK, 512, 0, stream>>>(colb, cursor, s1, dis, a2, N);
    head_kernel<<<512, 256, 0, stream>>>(a2, W2, b2, Wm1, bm1, Wm2, bm2, out, N);
}

// Round 4
// 428.030 us; speedup vs baseline: 4.0115x; 4.0115x over previous
//
#include <hip/hip_runtime.h>
#include <math.h>

// ---------------------------------------------------------------------------
// GNN pool: 2x GCNConv(elu) + MLP(128) + Linear(15) + softmax
// N=100000, E=3200000, IN=3, HID=64, MLP_HID=128, K=15, all fp32.
//
// Round-4 pipeline (hybrid of r2 + r3):
//   memset cursor -> scatter (bucket edges by dst>>7, LDS hist, packed
//   (dstLow7<<17)|src) -> bscan (bucket base offsets) -> csr_sort (per-bucket
//   LDS counting sort: row_ptr + deg/dis/sx + COALESCED col writes)
//   -> agg3 (wave/node, 3 feats) -> agg64 (wave/node, lane=feature, unroll 8)
//   -> head (fused W2/elu/Wm1/elu/Wm2/softmax).
//
// r2 lesson: fill_kernel's lone 4B scattered writes cost 197 MB HBM (16x amp).
// r3 lesson: per-bucket LDS-atomic aggregation is latency-serialized (1375us,
//   VALU 3.5%) — wave-per-node CSR aggregation is far better (more blocks, no
//   barriers, 8 loads in flight). So: bucket-sort builds the CSR, wave-per-node
//   consumes it.
// ---------------------------------------------------------------------------

#define SPAN 128          // nodes per bucket
#define CAP  4608         // bucket capacity (mean 4092, sd ~64: mean + 8 sigma)
#define CH   8192         // edges per scatter chunk
#define NT   16
#define NTP  17

// ---- counting scatter: edges -> buckets by dst>>7, packed (dl<<17)|src ----
__global__ __launch_bounds__(256) void scatter_kernel(const int* __restrict__ src,
    const int* __restrict__ dst, int* __restrict__ cursor, unsigned* __restrict__ colb,
    int E, int NBK, int nChunks) {
    __shared__ int hist[1024];
    __shared__ unsigned gb[1024];
    int tid = threadIdx.x;
    for (int chunk = blockIdx.x; chunk < nChunks; chunk += gridDim.x) {
        for (int i = tid; i < NBK; i += 256) hist[i] = 0;
        __syncthreads();
        int base = chunk * CH;
        int cnt = min(CH, E - base);
        unsigned br[32], dt[32];
#pragma unroll
        for (int j = 0; j < 32; ++j) {
            int idx = j * 256 + tid;
            br[j] = 0xFFFFFFFFu;
            if (idx < cnt) {
                int e = base + idx;
                int s = src[e], d = dst[e];
                int b = d >> 7;
                int r = atomicAdd(&hist[b], 1);
                br[j] = ((unsigned)b << 13) | (unsigned)r;   // b<1024 (10b), r<8192 (13b)
                dt[j] = ((unsigned)(d & 127) << 17) | (unsigned)s;  // src < 2^17
            }
        }
        __syncthreads();
        for (int b = tid; b < NBK; b += 256) {
            int c = hist[b];
            gb[b] = (unsigned)(b * CAP) + (c ? (unsigned)atomicAdd(&cursor[b], c) : 0u);
        }
        __syncthreads();
#pragma unroll
        for (int j = 0; j < 32; ++j) {
            if (br[j] != 0xFFFFFFFFu) {
                int b = br[j] >> 13;
                int r = br[j] & 8191;
                unsigned pos = gb[b] + (unsigned)r;
                if (pos < (unsigned)(b + 1) * CAP) colb[pos] = dt[j];  // overflow guard
            }
        }
        __syncthreads();
    }
}

// ---- exclusive scan over bucket counts -> bbase; row_ptr[N] = total ----
__global__ __launch_bounds__(1024) void bscan_kernel(const int* __restrict__ cursor,
    int* __restrict__ bbase, int* __restrict__ row_ptr, int NBK, int N) {
    __shared__ int ls[1024];
    int t = threadIdx.x;
    int v = (t < NBK) ? min(cursor[t], CAP) : 0;
    ls[t] = v;
    __syncthreads();
    for (int off = 1; off < 1024; off <<= 1) {
        int xv = (t >= off) ? ls[t - off] : 0;
        __syncthreads();
        ls[t] += xv;
        __syncthreads();
    }
    if (t < NBK) bbase[t] = ls[t] - v;     // exclusive
    if (t == NBK - 1) row_ptr[N] = ls[t];  // total kept edges
}

// ---- per-bucket counting sort: row_ptr, deg->dis, sx, coalesced col ----
__global__ __launch_bounds__(256) void csr_sort_kernel(const unsigned* __restrict__ colb,
    const int* __restrict__ cursor, const int* __restrict__ bbase,
    const float* __restrict__ x, int* __restrict__ row_ptr, int* __restrict__ col,
    float* __restrict__ dis, float* __restrict__ sx, int N) {
    __shared__ unsigned ebuf[CAP];
    __shared__ int sbuf[CAP];
    __shared__ int cnt[SPAN], pref[SPAN], fill[SPAN];
    int b = blockIdx.x, tid = threadIdx.x;
    int n = min(cursor[b], CAP);
    int base = b * CAP, bb = bbase[b];
    if (tid < SPAN) cnt[tid] = 0;
    for (int i = tid; i < n; i += 256) ebuf[i] = colb[base + i];
    __syncthreads();
    for (int i = tid; i < n; i += 256) atomicAdd(&cnt[(ebuf[i] >> 17) & 127], 1);
    __syncthreads();
    // exclusive prefix over 128 counts (Hillis-Steele)
    if (tid < SPAN) pref[tid] = cnt[tid];
    __syncthreads();
    for (int off = 1; off < SPAN; off <<= 1) {
        int xv = (tid < SPAN && tid >= off) ? pref[tid - off] : 0;
        __syncthreads();
        if (tid < SPAN) pref[tid] += xv;
        __syncthreads();
    }
    if (tid < SPAN) {
        int ex = pref[tid] - cnt[tid];
        fill[tid] = ex;
        int node = b * SPAN + tid;
        if (node < N) {
            row_ptr[node] = bb + ex;
            float r = rsqrtf((float)(cnt[tid] + 1));
            dis[node] = r;
            sx[node * 3 + 0] = r * x[node * 3 + 0];
            sx[node * 3 + 1] = r * x[node * 3 + 1];
            sx[node * 3 + 2] = r * x[node * 3 + 2];
        }
    }
    __syncthreads();
    for (int i = tid; i < n; i += 256) {
        unsigned e = ebuf[i];
        int pos = atomicAdd(&fill[(e >> 17) & 127], 1);
        sbuf[pos] = (int)(e & 0x1FFFF);
    }
    __syncthreads();
    for (int i = tid; i < n; i += 256) col[bb + i] = sbuf[i];  // coalesced
}

// ---- layer 1: aggregate sx (3 feats) + W1 transform + bias + elu; s1=dis*h1 ----
__global__ void agg3_kernel(const float* __restrict__ sx, const int* __restrict__ row_ptr,
                            const int* __restrict__ col, const float* __restrict__ dis,
                            const float* __restrict__ W1, const float* __restrict__ b1,
                            float* __restrict__ s1, int N) {
    int wave = (blockIdx.x * blockDim.x + threadIdx.x) >> 6;
    int lane = threadIdx.x & 63;
    if (wave >= N) return;
    int d = wave;
    int start = row_ptr[d], end = row_ptr[d + 1];
    float a0 = 0.f, a1 = 0.f, a2v = 0.f;
    for (int i = start + lane; i < end; i += 64) {
        int s = col[i];
        a0  += sx[s * 3 + 0];
        a1  += sx[s * 3 + 1];
        a2v += sx[s * 3 + 2];
    }
#pragma unroll
    for (int off = 32; off; off >>= 1) {
        a0  += __shfl_xor(a0, off);
        a1  += __shfl_xor(a1, off);
        a2v += __shfl_xor(a2v, off);
    }
    a0  += sx[d * 3 + 0];   // self loop
    a1  += sx[d * 3 + 1];
    a2v += sx[d * 3 + 2];
    float r = dis[d];
    float v = r * (a0 * W1[lane] + a1 * W1[64 + lane] + a2v * W1[128 + lane]) + b1[lane];
    v = (v > 0.f) ? v : expm1f(v);
    s1[(size_t)d * 64 + lane] = r * v;  // pre-scaled for next aggregation
}

// ---- layer 2 aggregation: a2[d] = dis[d]*(sum_nbr s1[s] + s1[d]), unroll 8 ----
__global__ void agg64_kernel(const float* __restrict__ s1, const int* __restrict__ row_ptr,
                             const int* __restrict__ col, const float* __restrict__ dis,
                             float* __restrict__ a2, int N) {
    int wave = (blockIdx.x * blockDim.x + threadIdx.x) >> 6;
    int lane = threadIdx.x & 63;
    if (wave >= N) return;
    int d = wave;
    int start = row_ptr[d], end = row_ptr[d + 1];
    float acc0 = s1[(size_t)d * 64 + lane];  // self loop
    float acc1 = 0.f, acc2 = 0.f, acc3 = 0.f;
    float acc4 = 0.f, acc5 = 0.f, acc6 = 0.f, acc7 = 0.f;
    int i = start;
    for (; i + 7 < end; i += 8) {
        int c0 = col[i],     c1 = col[i + 1], c2 = col[i + 2], c3 = col[i + 3];
        int c4 = col[i + 4], c5 = col[i + 5], c6 = col[i + 6], c7 = col[i + 7];
        acc0 += s1[(size_t)c0 * 64 + lane];
        acc1 += s1[(size_t)c1 * 64 + lane];
        acc2 += s1[(size_t)c2 * 64 + lane];
        acc3 += s1[(size_t)c3 * 64 + lane];
        acc4 += s1[(size_t)c4 * 64 + lane];
        acc5 += s1[(size_t)c5 * 64 + lane];
        acc6 += s1[(size_t)c6 * 64 + lane];
        acc7 += s1[(size_t)c7 * 64 + lane];
    }
    for (; i < end; ++i) acc0 += s1[(size_t)col[i] * 64 + lane];
    a2[(size_t)d * 64 + lane] = dis[d] *
        (((acc0 + acc1) + (acc2 + acc3)) + ((acc4 + acc5) + (acc6 + acc7)));
}

// ---- fused head: out = softmax(elu(elu(a2@W2+b2)@Wm1+bm1)@Wm2+bm2) ----
__global__ __launch_bounds__(256) void head_kernel(const float* __restrict__ a2,
    const float* __restrict__ W2g, const float* __restrict__ b2g,
    const float* __restrict__ Wm1g, const float* __restrict__ bm1g,
    const float* __restrict__ Wm2g, const float* __restrict__ bm2g,
    float* __restrict__ out, int N) {
    __shared__ float W2s[64 * 64];
    __shared__ float Wm1s[64 * 128];
    __shared__ float b2s[64];
    __shared__ float bm1s[128];
    __shared__ float bm2s[16];
    __shared__ float at[64 * NTP];
    __shared__ float tt[64 * NTP];
    __shared__ float mt[NT * 129];
    __shared__ float ot[NT * 16];
    int tid = threadIdx.x;
    for (int i = tid; i < 64 * 64;  i += 256) W2s[i]  = W2g[i];
    for (int i = tid; i < 64 * 128; i += 256) Wm1s[i] = Wm1g[i];
    if (tid < 64)  b2s[tid]  = b2g[tid];
    if (tid < 128) bm1s[tid] = bm1g[tid];
    if (tid < 16)  bm2s[tid] = (tid < 15) ? bm2g[tid] : 0.f;
    __syncthreads();

    int nTiles = (N + NT - 1) / NT;
    int f  = tid & 63;
    int n0 = (tid >> 6) * 4;
    int cc16 = tid & 15;
    int cn   = tid >> 4;
    int coff = (cc16 < 15) ? cc16 : 0;

    for (int tile = blockIdx.x; tile < nTiles; tile += gridDim.x) {
        int base = tile * NT;
        {
            int n = tid >> 6, k = tid & 63;
#pragma unroll
            for (int g = 0; g < 4; ++g) {
                int nn = n * 4 + g;
                int node = base + nn; if (node >= N) node = N - 1;
                at[k * NTP + nn] = a2[(size_t)node * 64 + k];
            }
        }
        __syncthreads();
        {
            float bb = b2s[f];
            float acc0 = bb, acc1 = bb, acc2 = bb, acc3 = bb;
#pragma unroll 4
            for (int k = 0; k < 64; ++k) {
                float w = W2s[k * 64 + f];
                const float* a = &at[k * NTP + n0];
                acc0 = fmaf(w, a[0], acc0);
                acc1 = fmaf(w, a[1], acc1);
                acc2 = fmaf(w, a[2], acc2);
                acc3 = fmaf(w, a[3], acc3);
            }
            float* t = &tt[f * NTP + n0];
            t[0] = (acc0 > 0.f) ? acc0 : expm1f(acc0);
            t[1] = (acc1 > 0.f) ? acc1 : expm1f(acc1);
            t[2] = (acc2 > 0.f) ? acc2 : expm1f(acc2);
            t[3] = (acc3 > 0.f) ? acc3 : expm1f(acc3);
        }
        __syncthreads();
#pragma unroll
        for (int pass = 0; pass < 2; ++pass) {
            int j = f + pass * 64;
            float bb = bm1s[j];
            float acc0 = bb, acc1 = bb, acc2 = bb, acc3 = bb;
#pragma unroll 4
            for (int ff = 0; ff < 64; ++ff) {
                float w = Wm1s[ff * 128 + j];
                const float* t = &tt[ff * NTP + n0];
                acc0 = fmaf(w, t[0], acc0);
                acc1 = fmaf(w, t[1], acc1);
                acc2 = fmaf(w, t[2], acc2);
                acc3 = fmaf(w, t[3], acc3);
            }
            mt[(n0 + 0) * 129 + j] = (acc0 > 0.f) ? acc0 : expm1f(acc0);
            mt[(n0 + 1) * 129 + j] = (acc1 > 0.f) ? acc1 : expm1f(acc1);
            mt[(n0 + 2) * 129 + j] = (acc2 > 0.f) ? acc2 : expm1f(acc2);
            mt[(n0 + 3) * 129 + j] = (acc3 > 0.f) ? acc3 : expm1f(acc3);
        }
        __syncthreads();
        {
            float acc = bm2s[cc16];
#pragma unroll 4
            for (int j = 0; j < 128; ++j) {
                acc = fmaf(mt[cn * 129 + j], Wm2g[j * 15 + coff], acc);
            }
            if (cc16 < 15) ot[cn * 16 + cc16] = acc;
        }
        __syncthreads();
        {
            int node = base + cn;
            if (cc16 < 15 && node < N) {
                float mx = -1e30f;
#pragma unroll
                for (int c2 = 0; c2 < 15; ++c2) mx = fmaxf(mx, ot[cn * 16 + c2]);
                float ssum = 0.f;
#pragma unroll
                for (int c2 = 0; c2 < 15; ++c2) ssum += __expf(ot[cn * 16 + c2] - mx);
                out[(size_t)node * 15 + cc16] = __expf(ot[cn * 16 + cc16] - mx) / ssum;
            }
        }
        __syncthreads();
    }
}

extern "C" void kernel_launch(void* const* d_in, const int* in_sizes, int n_in,
                              void* d_out, int out_size, void* d_ws, size_t ws_size,
                              hipStream_t stream) {
    const float* x   = (const float*)d_in[0];
    const int*   ei  = (const int*)d_in[1];
    const float* W1  = (const float*)d_in[2];
    const float* b1  = (const float*)d_in[3];
    const float* W2  = (const float*)d_in[4];
    const float* b2  = (const float*)d_in[5];
    const float* Wm1 = (const float*)d_in[6];
    const float* bm1 = (const float*)d_in[7];
    const float* Wm2 = (const float*)d_in[8];
    const float* bm2 = (const float*)d_in[9];
    float* out = (float*)d_out;

    int N = in_sizes[0] / 3;
    int E = in_sizes[1] / 2;
    const int* src = ei;
    const int* dst = ei + E;
    int NBK = (N + SPAN - 1) / SPAN;   // 782

    uintptr_t p = (uintptr_t)d_ws;
    auto carve = [&](size_t bytes) -> void* {
        p = (p + 255) & ~(uintptr_t)255;
        void* r = (void*)p;
        p += bytes;
        return r;
    };
    int*   cursor  = (int*)carve((size_t)NBK * 4);
    int*   bbase   = (int*)carve((size_t)NBK * 4);
    int*   row_ptr = (int*)carve((size_t)(N + 1) * 4);
    float* dis     = (float*)carve((size_t)N * 4);
    float* sx      = (float*)carve((size_t)N * 12);
    int*   col     = (int*)carve((size_t)E * 4);
    float* s1      = (float*)carve((size_t)N * 64 * 4);
    float* a2      = (float*)carve((size_t)N * 64 * 4);
    // colb (14.4 MB) aliases a2 (25.6 MB): colb dead after csr_sort, a2 written in agg64
    unsigned* colb = (unsigned*)a2;

    hipMemsetAsync(cursor, 0, (size_t)NBK * 4, stream);

    int nChunks = (E + CH - 1) / CH;
    int waveBlocks = (N + 3) / 4;  // 4 waves (nodes) per 256-thread block
    scatter_kernel<<<nChunks, 256, 0, stream>>>(src, dst, cursor, colb, E, NBK, nChunks);
    bscan_kernel<<<1, 1024, 0, stream>>>(cursor, bbase, row_ptr, NBK, N);
    csr_sort_kernel<<<NBK, 256, 0, stream>>>(colb, cursor, bbase, x, row_ptr, col, dis, sx, N);
    agg3_kernel<<<waveBlocks, 256, 0, stream>>>(sx, row_ptr, col, dis, W1, b1, s1, N);
    agg64_kernel<<<waveBlocks, 256, 0, stream>>>(s1, row_ptr, col, dis, a2, N);
    head_kernel<<<512, 256, 0, stream>>>(a2, W2, b2, Wm1, bm1, Wm2, bm2, out, N);
}

// Round 5
// 372.852 us; speedup vs baseline: 4.6051x; 1.1480x over previous
//
#include <hip/hip_runtime.h>
#include <math.h>

// ---------------------------------------------------------------------------
// GNN pool: 2x GCNConv(elu) + MLP(128) + Linear(15) + softmax
// N=100000, E=3200000, IN=3, HID=64, MLP_HID=128, K=15, all fp32.
//
// Round-5 pipeline:
//   scatter (bucket by dst>>7) -> bscan -> csr_sort (LDS counting sort,
//   coalesced col) -> agg3 (wave/node) -> agg64 (wave/node, unroll 8)
//   -> h1 (a2@W2 elu @Wm1 elu -> m^T, register-blocked 8x4 / 8x8, b128 LDS)
//   -> h2 (m^T @ Wm2 + softmax, thread/node, b128 broadcast weights)
//
// r4 lesson: old fused head was LDS-issue-bound (VALU 29%, ~1200 ds_read_b32
// vs ~900 FMA per thread-tile). Fix = register blocking so each b128 LDS read
// feeds >=16 FMAs; stage A reads a2/W2 from global (L1) with zero LDS.
// ---------------------------------------------------------------------------

#define SPAN 128          // nodes per bucket
#define CAP  4608         // bucket capacity (mean 4092 + ~8 sigma)
#define CH   8192         // edges per scatter chunk
#define HNT  128          // nodes per h1 tile

__device__ __forceinline__ float elu(float v) { return v > 0.f ? v : expm1f(v); }

// ---- counting scatter: edges -> buckets by dst>>7, packed (dl<<17)|src ----
__global__ __launch_bounds__(256) void scatter_kernel(const int* __restrict__ src,
    const int* __restrict__ dst, int* __restrict__ cursor, unsigned* __restrict__ colb,
    int E, int NBK, int nChunks) {
    __shared__ int hist[1024];
    __shared__ unsigned gb[1024];
    int tid = threadIdx.x;
    for (int chunk = blockIdx.x; chunk < nChunks; chunk += gridDim.x) {
        for (int i = tid; i < NBK; i += 256) hist[i] = 0;
        __syncthreads();
        int base = chunk * CH;
        int cnt = min(CH, E - base);
        unsigned br[32], dt[32];
#pragma unroll
        for (int j = 0; j < 32; ++j) {
            int idx = j * 256 + tid;
            br[j] = 0xFFFFFFFFu;
            if (idx < cnt) {
                int e = base + idx;
                int s = src[e], d = dst[e];
                int b = d >> 7;
                int r = atomicAdd(&hist[b], 1);
                br[j] = ((unsigned)b << 13) | (unsigned)r;
                dt[j] = ((unsigned)(d & 127) << 17) | (unsigned)s;
            }
        }
        __syncthreads();
        for (int b = tid; b < NBK; b += 256) {
            int c = hist[b];
            gb[b] = (unsigned)(b * CAP) + (c ? (unsigned)atomicAdd(&cursor[b], c) : 0u);
        }
        __syncthreads();
#pragma unroll
        for (int j = 0; j < 32; ++j) {
            if (br[j] != 0xFFFFFFFFu) {
                int b = br[j] >> 13;
                int r = br[j] & 8191;
                unsigned pos = gb[b] + (unsigned)r;
                if (pos < (unsigned)(b + 1) * CAP) colb[pos] = dt[j];
            }
        }
        __syncthreads();
    }
}

// ---- exclusive scan over bucket counts -> bbase ----
__global__ __launch_bounds__(1024) void bscan_kernel(const int* __restrict__ cursor,
    int* __restrict__ bbase, int* __restrict__ row_ptr, int NBK, int N) {
    __shared__ int ls[1024];
    int t = threadIdx.x;
    int v = (t < NBK) ? min(cursor[t], CAP) : 0;
    ls[t] = v;
    __syncthreads();
    for (int off = 1; off < 1024; off <<= 1) {
        int xv = (t >= off) ? ls[t - off] : 0;
        __syncthreads();
        ls[t] += xv;
        __syncthreads();
    }
    if (t < NBK) bbase[t] = ls[t] - v;
    if (t == NBK - 1) row_ptr[N] = ls[t];
}

// ---- per-bucket counting sort: row_ptr, deg->dis, sx, coalesced col ----
__global__ __launch_bounds__(256) void csr_sort_kernel(const unsigned* __restrict__ colb,
    const int* __restrict__ cursor, const int* __restrict__ bbase,
    const float* __restrict__ x, int* __restrict__ row_ptr, int* __restrict__ col,
    float* __restrict__ dis, float* __restrict__ sx, int N) {
    __shared__ unsigned ebuf[CAP];
    __shared__ int sbuf[CAP];
    __shared__ int cnt[SPAN], pref[SPAN], fill[SPAN];
    int b = blockIdx.x, tid = threadIdx.x;
    int n = min(cursor[b], CAP);
    int base = b * CAP, bb = bbase[b];
    if (tid < SPAN) cnt[tid] = 0;
    for (int i = tid; i < n; i += 256) ebuf[i] = colb[base + i];
    __syncthreads();
    for (int i = tid; i < n; i += 256) atomicAdd(&cnt[(ebuf[i] >> 17) & 127], 1);
    __syncthreads();
    if (tid < SPAN) pref[tid] = cnt[tid];
    __syncthreads();
    for (int off = 1; off < SPAN; off <<= 1) {
        int xv = (tid < SPAN && tid >= off) ? pref[tid - off] : 0;
        __syncthreads();
        if (tid < SPAN) pref[tid] += xv;
        __syncthreads();
    }
    if (tid < SPAN) {
        int ex = pref[tid] - cnt[tid];
        fill[tid] = ex;
        int node = b * SPAN + tid;
        if (node < N) {
            row_ptr[node] = bb + ex;
            float r = rsqrtf((float)(cnt[tid] + 1));
            dis[node] = r;
            sx[node * 3 + 0] = r * x[node * 3 + 0];
            sx[node * 3 + 1] = r * x[node * 3 + 1];
            sx[node * 3 + 2] = r * x[node * 3 + 2];
        }
    }
    __syncthreads();
    for (int i = tid; i < n; i += 256) {
        unsigned e = ebuf[i];
        int pos = atomicAdd(&fill[(e >> 17) & 127], 1);
        sbuf[pos] = (int)(e & 0x1FFFF);
    }
    __syncthreads();
    for (int i = tid; i < n; i += 256) col[bb + i] = sbuf[i];
}

// ---- layer 1: aggregate sx (3 feats) + W1 transform + bias + elu; s1=dis*h1 ----
__global__ void agg3_kernel(const float* __restrict__ sx, const int* __restrict__ row_ptr,
                            const int* __restrict__ col, const float* __restrict__ dis,
                            const float* __restrict__ W1, const float* __restrict__ b1,
                            float* __restrict__ s1, int N) {
    int wave = (blockIdx.x * blockDim.x + threadIdx.x) >> 6;
    int lane = threadIdx.x & 63;
    if (wave >= N) return;
    int d = wave;
    int start = row_ptr[d], end = row_ptr[d + 1];
    float a0 = 0.f, a1 = 0.f, a2v = 0.f;
    for (int i = start + lane; i < end; i += 64) {
        int s = col[i];
        a0  += sx[s * 3 + 0];
        a1  += sx[s * 3 + 1];
        a2v += sx[s * 3 + 2];
    }
#pragma unroll
    for (int off = 32; off; off >>= 1) {
        a0  += __shfl_xor(a0, off);
        a1  += __shfl_xor(a1, off);
        a2v += __shfl_xor(a2v, off);
    }
    a0  += sx[d * 3 + 0];
    a1  += sx[d * 3 + 1];
    a2v += sx[d * 3 + 2];
    float r = dis[d];
    float v = r * (a0 * W1[lane] + a1 * W1[64 + lane] + a2v * W1[128 + lane]) + b1[lane];
    s1[(size_t)d * 64 + lane] = r * elu(v);
}

// ---- layer 2 aggregation: a2[d] = dis[d]*(sum_nbr s1[s] + s1[d]), unroll 8 ----
__global__ void agg64_kernel(const float* __restrict__ s1, const int* __restrict__ row_ptr,
                             const int* __restrict__ col, const float* __restrict__ dis,
                             float* __restrict__ a2, int N) {
    int wave = (blockIdx.x * blockDim.x + threadIdx.x) >> 6;
    int lane = threadIdx.x & 63;
    if (wave >= N) return;
    int d = wave;
    int start = row_ptr[d], end = row_ptr[d + 1];
    float acc0 = s1[(size_t)d * 64 + lane];
    float acc1 = 0.f, acc2 = 0.f, acc3 = 0.f;
    float acc4 = 0.f, acc5 = 0.f, acc6 = 0.f, acc7 = 0.f;
    int i = start;
    for (; i + 7 < end; i += 8) {
        int c0 = col[i],     c1 = col[i + 1], c2 = col[i + 2], c3 = col[i + 3];
        int c4 = col[i + 4], c5 = col[i + 5], c6 = col[i + 6], c7 = col[i + 7];
        acc0 += s1[(size_t)c0 * 64 + lane];
        acc1 += s1[(size_t)c1 * 64 + lane];
        acc2 += s1[(size_t)c2 * 64 + lane];
        acc3 += s1[(size_t)c3 * 64 + lane];
        acc4 += s1[(size_t)c4 * 64 + lane];
        acc5 += s1[(size_t)c5 * 64 + lane];
        acc6 += s1[(size_t)c6 * 64 + lane];
        acc7 += s1[(size_t)c7 * 64 + lane];
    }
    for (; i < end; ++i) acc0 += s1[(size_t)col[i] * 64 + lane];
    a2[(size_t)d * 64 + lane] = dis[d] *
        (((acc0 + acc1) + (acc2 + acc3)) + ((acc4 + acc5) + (acc6 + acc7)));
}

// ---- h1: m^T = elu(elu(a2@W2+b2)@Wm1+bm1)^T, register-blocked ----
// Stage A: thread = 8f x 4n, a2/W2 from global (L1). Stage B: 8j x 8n, b128 LDS.
__global__ __launch_bounds__(256) void h1_kernel(const float* __restrict__ a2,
    const float* __restrict__ W2g, const float* __restrict__ b2g,
    const float* __restrict__ Wm1g, const float* __restrict__ bm1g,
    float* __restrict__ mt, int N) {
    __shared__ float Wm1s[64 * 128];   // [f][j] 32 KB
    __shared__ float tt[64 * 128];     // [f][n] h2 tile, 32 KB
    __shared__ float b2s[64];
    __shared__ float bm1s[128];
    int tid = threadIdx.x;
    for (int i = tid; i < 64 * 128; i += 256) Wm1s[i] = Wm1g[i];
    if (tid < 64)  b2s[tid]  = b2g[tid];
    if (tid < 128) bm1s[tid] = bm1g[tid];
    __syncthreads();

    int fA = (tid & 7) * 8;       // stage A: 8 consecutive output features
    int nA = (tid >> 3) * 4;      // stage A: 4 consecutive nodes (0..124)
    int jB = (tid & 15) * 8;      // stage B: 8 consecutive j
    int nB = (tid >> 4) * 8;      // stage B: 8 consecutive nodes (0..120)

    int nTiles = (N + HNT - 1) / HNT;
    for (int tile = blockIdx.x; tile < nTiles; tile += gridDim.x) {
        int base = tile * HNT;
        // ---- stage A: acc[8f][4n] over k=0..63; a2 & W2 from global ----
        float acc[8][4];
#pragma unroll
        for (int f = 0; f < 8; ++f) {
            float bb = b2s[fA + f];
#pragma unroll
            for (int i = 0; i < 4; ++i) acc[f][i] = bb;
        }
        const float* ar0 = a2 + (size_t)min(base + nA + 0, N - 1) * 64;
        const float* ar1 = a2 + (size_t)min(base + nA + 1, N - 1) * 64;
        const float* ar2 = a2 + (size_t)min(base + nA + 2, N - 1) * 64;
        const float* ar3 = a2 + (size_t)min(base + nA + 3, N - 1) * 64;
#pragma unroll 4
        for (int k = 0; k < 64; k += 4) {
            float4 q0 = *(const float4*)(ar0 + k);
            float4 q1 = *(const float4*)(ar1 + k);
            float4 q2 = *(const float4*)(ar2 + k);
            float4 q3 = *(const float4*)(ar3 + k);
            float av0[4] = {q0.x, q0.y, q0.z, q0.w};
            float av1[4] = {q1.x, q1.y, q1.z, q1.w};
            float av2[4] = {q2.x, q2.y, q2.z, q2.w};
            float av3[4] = {q3.x, q3.y, q3.z, q3.w};
#pragma unroll
            for (int kk = 0; kk < 4; ++kk) {
                float4 wlo = *(const float4*)(W2g + (k + kk) * 64 + fA);
                float4 whi = *(const float4*)(W2g + (k + kk) * 64 + fA + 4);
                float wv[8] = {wlo.x, wlo.y, wlo.z, wlo.w, whi.x, whi.y, whi.z, whi.w};
#pragma unroll
                for (int f = 0; f < 8; ++f) {
                    acc[f][0] = fmaf(wv[f], av0[kk], acc[f][0]);
                    acc[f][1] = fmaf(wv[f], av1[kk], acc[f][1]);
                    acc[f][2] = fmaf(wv[f], av2[kk], acc[f][2]);
                    acc[f][3] = fmaf(wv[f], av3[kk], acc[f][3]);
                }
            }
        }
#pragma unroll
        for (int f = 0; f < 8; ++f) {
            float4 v;
            v.x = elu(acc[f][0]); v.y = elu(acc[f][1]);
            v.z = elu(acc[f][2]); v.w = elu(acc[f][3]);
            *(float4*)(tt + (fA + f) * 128 + nA) = v;
        }
        __syncthreads();
        // ---- stage B: accB[8j][8n] over f=0..63; Wm1/tt b128 LDS ----
        float accB[8][8];
#pragma unroll
        for (int j = 0; j < 8; ++j) {
            float bb = bm1s[jB + j];
#pragma unroll
            for (int i = 0; i < 8; ++i) accB[j][i] = bb;
        }
#pragma unroll 4
        for (int f = 0; f < 64; ++f) {
            float4 w0 = *(const float4*)(Wm1s + f * 128 + jB);
            float4 w1 = *(const float4*)(Wm1s + f * 128 + jB + 4);
            float4 t0 = *(const float4*)(tt + f * 128 + nB);
            float4 t1 = *(const float4*)(tt + f * 128 + nB + 4);
            float wv[8] = {w0.x, w0.y, w0.z, w0.w, w1.x, w1.y, w1.z, w1.w};
            float tv[8] = {t0.x, t0.y, t0.z, t0.w, t1.x, t1.y, t1.z, t1.w};
#pragma unroll
            for (int j = 0; j < 8; ++j)
#pragma unroll
                for (int i = 0; i < 8; ++i)
                    accB[j][i] = fmaf(wv[j], tv[i], accB[j][i]);
        }
        // write m transposed: mt[j][node], elu applied
        if (base + HNT <= N) {
#pragma unroll
            for (int j = 0; j < 8; ++j) {
                size_t row = (size_t)(jB + j) * N + base + nB;
                float4 v0, v1;
                v0.x = elu(accB[j][0]); v0.y = elu(accB[j][1]);
                v0.z = elu(accB[j][2]); v0.w = elu(accB[j][3]);
                v1.x = elu(accB[j][4]); v1.y = elu(accB[j][5]);
                v1.z = elu(accB[j][6]); v1.w = elu(accB[j][7]);
                *(float4*)(mt + row) = v0;
                *(float4*)(mt + row + 4) = v1;
            }
        } else {
#pragma unroll
            for (int j = 0; j < 8; ++j)
#pragma unroll
                for (int i = 0; i < 8; ++i) {
                    int node = base + nB + i;
                    if (node < N) mt[(size_t)(jB + j) * N + node] = elu(accB[j][i]);
                }
        }
        __syncthreads();
    }
}

// ---- h2: out = softmax(m^T' @ Wm2 + bm2), thread per node ----
__global__ __launch_bounds__(256) void h2_kernel(const float* __restrict__ mt,
    const float* __restrict__ Wm2g, const float* __restrict__ bm2g,
    float* __restrict__ out, int N) {
    __shared__ float Wt[15 * 128];   // transposed [c][j]
    int tid = threadIdx.x;
    for (int i = tid; i < 15 * 128; i += 256) {
        int c = i >> 7, j = i & 127;
        Wt[i] = Wm2g[j * 15 + c];
    }
    __syncthreads();
    int node = blockIdx.x * 256 + tid;
    if (node >= N) return;
    float lg[15];
#pragma unroll
    for (int c = 0; c < 15; ++c) lg[c] = bm2g[c];
#pragma unroll 4
    for (int j4 = 0; j4 < 128; j4 += 4) {
        float m0 = mt[(size_t)(j4 + 0) * N + node];
        float m1 = mt[(size_t)(j4 + 1) * N + node];
        float m2 = mt[(size_t)(j4 + 2) * N + node];
        float m3 = mt[(size_t)(j4 + 3) * N + node];
#pragma unroll
        for (int c = 0; c < 15; ++c) {
            float4 w = *(const float4*)(Wt + c * 128 + j4);
            lg[c] = fmaf(m0, w.x, fmaf(m1, w.y, fmaf(m2, w.z, fmaf(m3, w.w, lg[c]))));
        }
    }
    float mx = lg[0];
#pragma unroll
    for (int c = 1; c < 15; ++c) mx = fmaxf(mx, lg[c]);
    float ex[15], s = 0.f;
#pragma unroll
    for (int c = 0; c < 15; ++c) { ex[c] = __expf(lg[c] - mx); s += ex[c]; }
    float inv = 1.f / s;
#pragma unroll
    for (int c = 0; c < 15; ++c) out[(size_t)node * 15 + c] = ex[c] * inv;
}

extern "C" void kernel_launch(void* const* d_in, const int* in_sizes, int n_in,
                              void* d_out, int out_size, void* d_ws, size_t ws_size,
                              hipStream_t stream) {
    const float* x   = (const float*)d_in[0];
    const int*   ei  = (const int*)d_in[1];
    const float* W1  = (const float*)d_in[2];
    const float* b1  = (const float*)d_in[3];
    const float* W2  = (const float*)d_in[4];
    const float* b2  = (const float*)d_in[5];
    const float* Wm1 = (const float*)d_in[6];
    const float* bm1 = (const float*)d_in[7];
    const float* Wm2 = (const float*)d_in[8];
    const float* bm2 = (const float*)d_in[9];
    float* out = (float*)d_out;

    int N = in_sizes[0] / 3;
    int E = in_sizes[1] / 2;
    const int* src = ei;
    const int* dst = ei + E;
    int NBK = (N + SPAN - 1) / SPAN;   // 782

    uintptr_t p = (uintptr_t)d_ws;
    auto carve = [&](size_t bytes) -> void* {
        p = (p + 255) & ~(uintptr_t)255;
        void* r = (void*)p;
        p += bytes;
        return r;
    };
    // a2 first (live through h1); everything else lives in the mt region and
    // is dead before h1 writes mt.
    float* a2 = (float*)carve((size_t)N * 64 * 4);
    float* mt = (float*)carve((size_t)N * 128 * 4);   // [128][N] m transposed
    uintptr_t q = (uintptr_t)mt;
    auto carve2 = [&](size_t bytes) -> void* {
        q = (q + 255) & ~(uintptr_t)255;
        void* r = (void*)q;
        q += bytes;
        return r;
    };
    int*   cursor  = (int*)carve2((size_t)NBK * 4);
    int*   bbase   = (int*)carve2((size_t)NBK * 4);
    int*   row_ptr = (int*)carve2((size_t)(N + 1) * 4);
    float* dis     = (float*)carve2((size_t)N * 4);
    float* sx      = (float*)carve2((size_t)N * 12);
    int*   col     = (int*)carve2((size_t)E * 4);
    float* s1      = (float*)carve2((size_t)N * 64 * 4);
    // colb (14.4 MB) aliases a2 (25.6 MB): dead after csr_sort; a2 written in agg64
    unsigned* colb = (unsigned*)a2;

    hipMemsetAsync(cursor, 0, (size_t)NBK * 4, stream);

    int nChunks = (E + CH - 1) / CH;
    int waveBlocks = (N + 3) / 4;
    int nTiles = (N + HNT - 1) / HNT;
    scatter_kernel<<<nChunks, 256, 0, stream>>>(src, dst, cursor, colb, E, NBK, nChunks);
    bscan_kernel<<<1, 1024, 0, stream>>>(cursor, bbase, row_ptr, NBK, N);
    csr_sort_kernel<<<NBK, 256, 0, stream>>>(colb, cursor, bbase, x, row_ptr, col, dis, sx, N);
    agg3_kernel<<<waveBlocks, 256, 0, stream>>>(sx, row_ptr, col, dis, W1, b1, s1, N);
    agg64_kernel<<<waveBlocks, 256, 0, stream>>>(s1, row_ptr, col, dis, a2, N);
    h1_kernel<<<nTiles, 256, 0, stream>>>(a2, W2, b2, Wm1, bm1, mt, N);
    h2_kernel<<<(N + 255) / 256, 256, 0, stream>>>(mt, Wm2, bm2, out, N);
}

// Round 6
// 346.671 us; speedup vs baseline: 4.9529x; 1.0755x over previous
//
#include <hip/hip_runtime.h>
#include <hip/hip_fp16.h>
#include <math.h>

// ---------------------------------------------------------------------------
// GNN pool: 2x GCNConv(elu) + MLP(128) + Linear(15) + softmax
// N=100000, E=3200000, IN=3, HID=64, MLP_HID=128, K=15, fp32 in/out.
//
// Round-6 pipeline:
//   scatter (bucket by dst>>7) -> bscan -> csr_sort (LDS counting sort,
//   coalesced col, sx padded float4) -> agg3 (wave/node, float4 sx, writes
//   s1 in FP16) -> agg64 (2 nodes/wave, half2 gathers: 128 B/edge instead of
//   256 B) -> head (fused: a2@W2 elu @Wm1 elu @Wm2 softmax -> out; m-tile
//   kept in LDS by aliasing dead Wm1s/tt; softmax via shfl_xor pair).
//
// r5 lesson: agg64 was the leader at 112.8us moving 819 MB of fp32 gathers
// (362 MB missing to HBM). fp16 s1 halves bytes AND footprint (12.8 MB).
// r4 lesson (still applies): head must be register-blocked; LDS reads must be
// b128 feeding >=16 FMAs each.
// ---------------------------------------------------------------------------

#define SPAN 128          // nodes per bucket
#define CAP  4608         // bucket capacity (mean 4092 + ~8 sigma)
#define CH   8192         // edges per scatter chunk
#define MSP  132          // m-tile row pad (16B-aligned rows, spreads banks)

__device__ __forceinline__ float elu(float v) { return v > 0.f ? v : expm1f(v); }

// ---- counting scatter: edges -> buckets by dst>>7, packed (dl<<17)|src ----
__global__ __launch_bounds__(256) void scatter_kernel(const int* __restrict__ src,
    const int* __restrict__ dst, int* __restrict__ cursor, unsigned* __restrict__ colb,
    int E, int NBK, int nChunks) {
    __shared__ int hist[1024];
    __shared__ unsigned gb[1024];
    int tid = threadIdx.x;
    for (int chunk = blockIdx.x; chunk < nChunks; chunk += gridDim.x) {
        for (int i = tid; i < NBK; i += 256) hist[i] = 0;
        __syncthreads();
        int base = chunk * CH;
        int cnt = min(CH, E - base);
        unsigned br[32], dt[32];
#pragma unroll
        for (int j = 0; j < 32; ++j) {
            int idx = j * 256 + tid;
            br[j] = 0xFFFFFFFFu;
            if (idx < cnt) {
                int e = base + idx;
                int s = src[e], d = dst[e];
                int b = d >> 7;
                int r = atomicAdd(&hist[b], 1);
                br[j] = ((unsigned)b << 13) | (unsigned)r;
                dt[j] = ((unsigned)(d & 127) << 17) | (unsigned)s;
            }
        }
        __syncthreads();
        for (int b = tid; b < NBK; b += 256) {
            int c = hist[b];
            gb[b] = (unsigned)(b * CAP) + (c ? (unsigned)atomicAdd(&cursor[b], c) : 0u);
        }
        __syncthreads();
#pragma unroll
        for (int j = 0; j < 32; ++j) {
            if (br[j] != 0xFFFFFFFFu) {
                int b = br[j] >> 13;
                int r = br[j] & 8191;
                unsigned pos = gb[b] + (unsigned)r;
                if (pos < (unsigned)(b + 1) * CAP) colb[pos] = dt[j];
            }
        }
        __syncthreads();
    }
}

// ---- exclusive scan over bucket counts -> bbase ----
__global__ __launch_bounds__(1024) void bscan_kernel(const int* __restrict__ cursor,
    int* __restrict__ bbase, int* __restrict__ row_ptr, int NBK, int N) {
    __shared__ int ls[1024];
    int t = threadIdx.x;
    int v = (t < NBK) ? min(cursor[t], CAP) : 0;
    ls[t] = v;
    __syncthreads();
    for (int off = 1; off < 1024; off <<= 1) {
        int xv = (t >= off) ? ls[t - off] : 0;
        __syncthreads();
        ls[t] += xv;
        __syncthreads();
    }
    if (t < NBK) bbase[t] = ls[t] - v;
    if (t == NBK - 1) row_ptr[N] = ls[t];
}

// ---- per-bucket counting sort: row_ptr, deg->dis, sx4, coalesced col ----
__global__ __launch_bounds__(256) void csr_sort_kernel(const unsigned* __restrict__ colb,
    const int* __restrict__ cursor, const int* __restrict__ bbase,
    const float* __restrict__ x, int* __restrict__ row_ptr, int* __restrict__ col,
    float* __restrict__ dis, float4* __restrict__ sx4, int N) {
    __shared__ unsigned ebuf[CAP];
    __shared__ int sbuf[CAP];
    __shared__ int cnt[SPAN], pref[SPAN], fill[SPAN];
    int b = blockIdx.x, tid = threadIdx.x;
    int n = min(cursor[b], CAP);
    int base = b * CAP, bb = bbase[b];
    if (tid < SPAN) cnt[tid] = 0;
    for (int i = tid; i < n; i += 256) ebuf[i] = colb[base + i];
    __syncthreads();
    for (int i = tid; i < n; i += 256) atomicAdd(&cnt[(ebuf[i] >> 17) & 127], 1);
    __syncthreads();
    if (tid < SPAN) pref[tid] = cnt[tid];
    __syncthreads();
    for (int off = 1; off < SPAN; off <<= 1) {
        int xv = (tid < SPAN && tid >= off) ? pref[tid - off] : 0;
        __syncthreads();
        if (tid < SPAN) pref[tid] += xv;
        __syncthreads();
    }
    if (tid < SPAN) {
        int ex = pref[tid] - cnt[tid];
        fill[tid] = ex;
        int node = b * SPAN + tid;
        if (node < N) {
            row_ptr[node] = bb + ex;
            float r = rsqrtf((float)(cnt[tid] + 1));
            dis[node] = r;
            float4 q;
            q.x = r * x[node * 3 + 0];
            q.y = r * x[node * 3 + 1];
            q.z = r * x[node * 3 + 2];
            q.w = 0.f;
            sx4[node] = q;
        }
    }
    __syncthreads();
    for (int i = tid; i < n; i += 256) {
        unsigned e = ebuf[i];
        int pos = atomicAdd(&fill[(e >> 17) & 127], 1);
        sbuf[pos] = (int)(e & 0x1FFFF);
    }
    __syncthreads();
    for (int i = tid; i < n; i += 256) col[bb + i] = sbuf[i];
}

// ---- layer 1: aggregate sx (float4) + W1 + bias + elu; s1h = fp16(dis*h1) ----
__global__ void agg3_kernel(const float4* __restrict__ sx4, const int* __restrict__ row_ptr,
                            const int* __restrict__ col, const float* __restrict__ dis,
                            const float* __restrict__ W1, const float* __restrict__ b1,
                            __half* __restrict__ s1h, int N) {
    int wave = (blockIdx.x * blockDim.x + threadIdx.x) >> 6;
    int lane = threadIdx.x & 63;
    if (wave >= N) return;
    int d = wave;
    int start = row_ptr[d], end = row_ptr[d + 1];
    float a0 = 0.f, a1 = 0.f, a2v = 0.f;
    for (int i = start + lane; i < end; i += 64) {
        float4 q = sx4[col[i]];
        a0 += q.x; a1 += q.y; a2v += q.z;
    }
#pragma unroll
    for (int off = 32; off; off >>= 1) {
        a0  += __shfl_xor(a0, off);
        a1  += __shfl_xor(a1, off);
        a2v += __shfl_xor(a2v, off);
    }
    float4 qd = sx4[d];   // self loop
    a0 += qd.x; a1 += qd.y; a2v += qd.z;
    float r = dis[d];
    float v = r * (a0 * W1[lane] + a1 * W1[64 + lane] + a2v * W1[128 + lane]) + b1[lane];
    s1h[(size_t)d * 64 + lane] = __float2half(r * elu(v));
}

// ---- layer 2: 2 nodes/wave, half2 gathers (128 B/row), fp32 accum ----
__global__ void agg64_kernel(const __half2* __restrict__ s1h, const int* __restrict__ row_ptr,
                             const int* __restrict__ col, const float* __restrict__ dis,
                             float* __restrict__ a2, int N) {
    int wave = (blockIdx.x * blockDim.x + threadIdx.x) >> 6;
    int lane = threadIdx.x & 63;
    int hl = lane & 31;
    int d = wave * 2 + (lane >> 5);
    bool act = d < N;
    int start = 0, end = 0;
    if (act) { start = row_ptr[d]; end = row_ptr[d + 1]; }
    float a0x = 0.f, a0y = 0.f, a1x = 0.f, a1y = 0.f;
    float a2x = 0.f, a2y = 0.f, a3x = 0.f, a3y = 0.f;
    float a4x = 0.f, a4y = 0.f, a5x = 0.f, a5y = 0.f;
    float a6x = 0.f, a6y = 0.f, a7x = 0.f, a7y = 0.f;
    if (act) {   // self loop
        float2 v = __half22float2(s1h[(size_t)d * 32 + hl]);
        a0x = v.x; a0y = v.y;
    }
    int i = start;
    for (; i + 7 < end; i += 8) {
        int c0 = col[i],     c1 = col[i + 1], c2 = col[i + 2], c3 = col[i + 3];
        int c4 = col[i + 4], c5 = col[i + 5], c6 = col[i + 6], c7 = col[i + 7];
        float2 v0 = __half22float2(s1h[(size_t)c0 * 32 + hl]);
        float2 v1 = __half22float2(s1h[(size_t)c1 * 32 + hl]);
        float2 v2 = __half22float2(s1h[(size_t)c2 * 32 + hl]);
        float2 v3 = __half22float2(s1h[(size_t)c3 * 32 + hl]);
        float2 v4 = __half22float2(s1h[(size_t)c4 * 32 + hl]);
        float2 v5 = __half22float2(s1h[(size_t)c5 * 32 + hl]);
        float2 v6 = __half22float2(s1h[(size_t)c6 * 32 + hl]);
        float2 v7 = __half22float2(s1h[(size_t)c7 * 32 + hl]);
        a0x += v0.x; a0y += v0.y; a1x += v1.x; a1y += v1.y;
        a2x += v2.x; a2y += v2.y; a3x += v3.x; a3y += v3.y;
        a4x += v4.x; a4y += v4.y; a5x += v5.x; a5y += v5.y;
        a6x += v6.x; a6y += v6.y; a7x += v7.x; a7y += v7.y;
    }
    for (; i < end; ++i) {
        float2 v = __half22float2(s1h[(size_t)col[i] * 32 + hl]);
        a0x += v.x; a0y += v.y;
    }
    if (act) {
        float r = dis[d];
        float2 o;
        o.x = r * (((a0x + a1x) + (a2x + a3x)) + ((a4x + a5x) + (a6x + a7x)));
        o.y = r * (((a0y + a1y) + (a2y + a3y)) + ((a4y + a5y) + (a6y + a7y)));
        *(float2*)(a2 + (size_t)d * 64 + 2 * hl) = o;
    }
}

// ---- fused head: out = softmax(elu(elu(a2@W2+b2)@Wm1+bm1)@Wm2+bm2) ----
// Stage A: 8f x 4n regs, a2/W2 from global. Stage B: 8j x 8n regs, b128 LDS.
// Stage C: m-tile in LDS (aliases dead Wm1s/tt), 2 threads/node (8+7 classes),
// softmax reduced via shfl_xor(1). One 128-node tile per block.
__global__ __launch_bounds__(256) void head_kernel(const float* __restrict__ a2,
    const float* __restrict__ W2g, const float* __restrict__ b2g,
    const float* __restrict__ Wm1g, const float* __restrict__ bm1g,
    const float* __restrict__ Wm2g, const float* __restrict__ bm2g,
    float* __restrict__ out, int N) {
    __shared__ float smem[128 * MSP];     // 67.6 KB: {Wm1s | tt} then ms
    __shared__ float Wt2[16 * 128];       // Wm2 transposed [c][j], row 15 = 0
    __shared__ float b2s[64], bm1s[128], bm2s[16];
    float* Wm1s = smem;                   // [f][j] 64*128
    float* tt   = smem + 64 * 128;        // [f][n] 64*128
    float* ms   = smem;                   // [n][MSP] m tile (after stage B)
    int tid = threadIdx.x;
    for (int i = tid; i < 64 * 128; i += 256) Wm1s[i] = Wm1g[i];
    for (int i = tid; i < 16 * 128; i += 256) {
        int c = i >> 7, j = i & 127;
        Wt2[i] = (c < 15) ? Wm2g[j * 15 + c] : 0.f;
    }
    if (tid < 64)  b2s[tid]  = b2g[tid];
    if (tid < 128) bm1s[tid] = bm1g[tid];
    if (tid < 16)  bm2s[tid] = (tid < 15) ? bm2g[tid] : 0.f;
    __syncthreads();

    int base = blockIdx.x * 128;
    // ---- stage A: acc[8f][4n] over k=0..63; a2 & W2 from global (L1) ----
    {
        int fA = (tid & 7) * 8;
        int nA = (tid >> 3) * 4;
        float acc[8][4];
#pragma unroll
        for (int f = 0; f < 8; ++f) {
            float bb = b2s[fA + f];
#pragma unroll
            for (int i = 0; i < 4; ++i) acc[f][i] = bb;
        }
        const float* ar0 = a2 + (size_t)min(base + nA + 0, N - 1) * 64;
        const float* ar1 = a2 + (size_t)min(base + nA + 1, N - 1) * 64;
        const float* ar2 = a2 + (size_t)min(base + nA + 2, N - 1) * 64;
        const float* ar3 = a2 + (size_t)min(base + nA + 3, N - 1) * 64;
#pragma unroll 4
        for (int k = 0; k < 64; k += 4) {
            float4 q0 = *(const float4*)(ar0 + k);
            float4 q1 = *(const float4*)(ar1 + k);
            float4 q2 = *(const float4*)(ar2 + k);
            float4 q3 = *(const float4*)(ar3 + k);
            float av0[4] = {q0.x, q0.y, q0.z, q0.w};
            float av1[4] = {q1.x, q1.y, q1.z, q1.w};
            float av2[4] = {q2.x, q2.y, q2.z, q2.w};
            float av3[4] = {q3.x, q3.y, q3.z, q3.w};
#pragma unroll
            for (int kk = 0; kk < 4; ++kk) {
                float4 wlo = *(const float4*)(W2g + (k + kk) * 64 + fA);
                float4 whi = *(const float4*)(W2g + (k + kk) * 64 + fA + 4);
                float wv[8] = {wlo.x, wlo.y, wlo.z, wlo.w, whi.x, whi.y, whi.z, whi.w};
#pragma unroll
                for (int f = 0; f < 8; ++f) {
                    acc[f][0] = fmaf(wv[f], av0[kk], acc[f][0]);
                    acc[f][1] = fmaf(wv[f], av1[kk], acc[f][1]);
                    acc[f][2] = fmaf(wv[f], av2[kk], acc[f][2]);
                    acc[f][3] = fmaf(wv[f], av3[kk], acc[f][3]);
                }
            }
        }
#pragma unroll
        for (int f = 0; f < 8; ++f) {
            float4 v;
            v.x = elu(acc[f][0]); v.y = elu(acc[f][1]);
            v.z = elu(acc[f][2]); v.w = elu(acc[f][3]);
            *(float4*)(tt + (fA + f) * 128 + nA) = v;
        }
    }
    __syncthreads();
    // ---- stage B: accB[8j][8n] over f=0..63; Wm1/tt b128 LDS ----
    float accB[8][8];
    int jB = (tid & 15) * 8;
    int nB = (tid >> 4) * 8;
    {
#pragma unroll
        for (int j = 0; j < 8; ++j) {
            float bb = bm1s[jB + j];
#pragma unroll
            for (int i = 0; i < 8; ++i) accB[j][i] = bb;
        }
#pragma unroll 4
        for (int f = 0; f < 64; ++f) {
            float4 w0 = *(const float4*)(Wm1s + f * 128 + jB);
            float4 w1 = *(const float4*)(Wm1s + f * 128 + jB + 4);
            float4 t0 = *(const float4*)(tt + f * 128 + nB);
            float4 t1 = *(const float4*)(tt + f * 128 + nB + 4);
            float wv[8] = {w0.x, w0.y, w0.z, w0.w, w1.x, w1.y, w1.z, w1.w};
            float tv[8] = {t0.x, t0.y, t0.z, t0.w, t1.x, t1.y, t1.z, t1.w};
#pragma unroll
            for (int j = 0; j < 8; ++j)
#pragma unroll
                for (int i = 0; i < 8; ++i)
                    accB[j][i] = fmaf(wv[j], tv[i], accB[j][i]);
        }
    }
    __syncthreads();   // all Wm1s/tt reads done before ms overwrites them
    // ---- write m tile [n][j] with elu ----
#pragma unroll
    for (int i = 0; i < 8; ++i) {
        float4 v0, v1;
        v0.x = elu(accB[0][i]); v0.y = elu(accB[1][i]);
        v0.z = elu(accB[2][i]); v0.w = elu(accB[3][i]);
        v1.x = elu(accB[4][i]); v1.y = elu(accB[5][i]);
        v1.z = elu(accB[6][i]); v1.w = elu(accB[7][i]);
        *(float4*)(ms + (nB + i) * MSP + jB) = v0;
        *(float4*)(ms + (nB + i) * MSP + jB + 4) = v1;
    }
    __syncthreads();
    // ---- stage C: logits + softmax; thread = (node, half); shfl pair ----
    {
        int n = tid >> 1;
        int half = tid & 1;
        int node = base + n;
        int c0 = half * 8;              // half 0: classes 0..7, half 1: 8..14
        float lg[8];
#pragma unroll
        for (int c = 0; c < 8; ++c) lg[c] = bm2s[c0 + c];
#pragma unroll 4
        for (int j4 = 0; j4 < 128; j4 += 4) {
            float4 mv = *(const float4*)(ms + n * MSP + j4);
#pragma unroll
            for (int c = 0; c < 8; ++c) {
                float4 w = *(const float4*)(Wt2 + (c0 + c) * 128 + j4);
                lg[c] = fmaf(mv.x, w.x, fmaf(mv.y, w.y, fmaf(mv.z, w.z, fmaf(mv.w, w.w, lg[c]))));
            }
        }
        if (half) lg[7] = -1e30f;       // class 15 doesn't exist
        float mx = lg[0];
#pragma unroll
        for (int c = 1; c < 8; ++c) mx = fmaxf(mx, lg[c]);
        mx = fmaxf(mx, __shfl_xor(mx, 1));
        float ex[8], s = 0.f;
#pragma unroll
        for (int c = 0; c < 8; ++c) { ex[c] = __expf(lg[c] - mx); s += ex[c]; }
        s += __shfl_xor(s, 1);
        float inv = 1.f / s;
        int nc = half ? 7 : 8;
        if (node < N) {
            for (int c = 0; c < nc; ++c)
                out[(size_t)node * 15 + c0 + c] = ex[c] * inv;
        }
    }
}

extern "C" void kernel_launch(void* const* d_in, const int* in_sizes, int n_in,
                              void* d_out, int out_size, void* d_ws, size_t ws_size,
                              hipStream_t stream) {
    const float* x   = (const float*)d_in[0];
    const int*   ei  = (const int*)d_in[1];
    const float* W1  = (const float*)d_in[2];
    const float* b1  = (const float*)d_in[3];
    const float* W2  = (const float*)d_in[4];
    const float* b2  = (const float*)d_in[5];
    const float* Wm1 = (const float*)d_in[6];
    const float* bm1 = (const float*)d_in[7];
    const float* Wm2 = (const float*)d_in[8];
    const float* bm2 = (const float*)d_in[9];
    float* out = (float*)d_out;

    int N = in_sizes[0] / 3;
    int E = in_sizes[1] / 2;
    const int* src = ei;
    const int* dst = ei + E;
    int NBK = (N + SPAN - 1) / SPAN;   // 782

    uintptr_t p = (uintptr_t)d_ws;
    auto carve = [&](size_t bytes) -> void* {
        p = (p + 255) & ~(uintptr_t)255;
        void* r = (void*)p;
        p += bytes;
        return r;
    };
    float*    a2      = (float*)carve((size_t)N * 64 * 4);   // colb aliases this
    int*      cursor  = (int*)carve((size_t)NBK * 4);
    int*      bbase   = (int*)carve((size_t)NBK * 4);
    int*      row_ptr = (int*)carve((size_t)(N + 1) * 4);
    float*    dis     = (float*)carve((size_t)N * 4);
    float4*   sx4     = (float4*)carve((size_t)N * 16);
    int*      col     = (int*)carve((size_t)E * 4);
    __half*   s1h     = (__half*)carve((size_t)N * 64 * 2);
    // colb (14.4 MB) aliases a2 (25.6 MB): dead after csr_sort; a2 written in agg64
    unsigned* colb = (unsigned*)a2;

    hipMemsetAsync(cursor, 0, (size_t)NBK * 4, stream);

    int nChunks = (E + CH - 1) / CH;
    int waveBlocks3  = (N + 3) / 4;   // agg3: 1 node/wave, 4 waves/block
    int waveBlocks64 = (N + 7) / 8;   // agg64: 2 nodes/wave, 4 waves/block
    int nTiles = (N + 127) / 128;
    scatter_kernel<<<nChunks, 256, 0, stream>>>(src, dst, cursor, colb, E, NBK, nChunks);
    bscan_kernel<<<1, 1024, 0, stream>>>(cursor, bbase, row_ptr, NBK, N);
    csr_sort_kernel<<<NBK, 256, 0, stream>>>(colb, cursor, bbase, x, row_ptr, col, dis, sx4, N);
    agg3_kernel<<<waveBlocks3, 256, 0, stream>>>(sx4, row_ptr, col, dis, W1, b1, s1h, N);
    agg64_kernel<<<waveBlocks64, 256, 0, stream>>>((const __half2*)s1h, row_ptr, col, dis, a2, N);
    head_kernel<<<nTiles, 256, 0, stream>>>(a2, W2, b2, Wm1, bm1, Wm2, bm2, out, N);
}

// Round 7
// 314.545 us; speedup vs baseline: 5.4588x; 1.1021x over previous
//
#include <hip/hip_runtime.h>
#include <hip/hip_fp16.h>
#include <math.h>

// ---------------------------------------------------------------------------
// GNN pool: 2x GCNConv(elu) + MLP(128) + Linear(15) + softmax
// N=100000, E=3200000, IN=3, HID=64, MLP_HID=128, K=15, fp32 in/out.
//
// Round-7 pipeline:
//   scatter (bucket by dst>>7) -> bscan -> csr_sort (LDS counting sort)
//   -> agg3 (wave/node, writes s1 FP16) -> agg64 (2 nodes/wave, half2
//   gathers) -> h1 (a2@W2 elu @Wm1 elu -> mt FP16 [j][node]; LDS = tt only,
//   33 KB -> 4 blocks/CU; Wm1 read from global/L1) -> h2 (mt@Wm2 + softmax).
//
// r6 lesson: fusing h2 into the head cost more than the 102MB mt round-trip
// it saved: 6.6M LDS bank conflicts (m-tile stride 132 = 4 mod 32) + 76.8KB
// LDS -> 2 blocks/CU -> occupancy 8.7%. Split + LDS-lean h1 instead.
// ---------------------------------------------------------------------------

#define SPAN 128          // nodes per bucket
#define CAP  4608         // bucket capacity (mean 4092 + ~8 sigma)
#define CH   8192         // edges per scatter chunk

__device__ __forceinline__ float elu(float v) { return v > 0.f ? v : expm1f(v); }

// ---- counting scatter: edges -> buckets by dst>>7, packed (dl<<17)|src ----
__global__ __launch_bounds__(256) void scatter_kernel(const int* __restrict__ src,
    const int* __restrict__ dst, int* __restrict__ cursor, unsigned* __restrict__ colb,
    int E, int NBK, int nChunks) {
    __shared__ int hist[1024];
    __shared__ unsigned gb[1024];
    int tid = threadIdx.x;
    for (int chunk = blockIdx.x; chunk < nChunks; chunk += gridDim.x) {
        for (int i = tid; i < NBK; i += 256) hist[i] = 0;
        __syncthreads();
        int base = chunk * CH;
        int cnt = min(CH, E - base);
        unsigned br[32], dt[32];
#pragma unroll
        for (int j = 0; j < 32; ++j) {
            int idx = j * 256 + tid;
            br[j] = 0xFFFFFFFFu;
            if (idx < cnt) {
                int e = base + idx;
                int s = src[e], d = dst[e];
                int b = d >> 7;
                int r = atomicAdd(&hist[b], 1);
                br[j] = ((unsigned)b << 13) | (unsigned)r;
                dt[j] = ((unsigned)(d & 127) << 17) | (unsigned)s;
            }
        }
        __syncthreads();
        for (int b = tid; b < NBK; b += 256) {
            int c = hist[b];
            gb[b] = (unsigned)(b * CAP) + (c ? (unsigned)atomicAdd(&cursor[b], c) : 0u);
        }
        __syncthreads();
#pragma unroll
        for (int j = 0; j < 32; ++j) {
            if (br[j] != 0xFFFFFFFFu) {
                int b = br[j] >> 13;
                int r = br[j] & 8191;
                unsigned pos = gb[b] + (unsigned)r;
                if (pos < (unsigned)(b + 1) * CAP) colb[pos] = dt[j];
            }
        }
        __syncthreads();
    }
}

// ---- exclusive scan over bucket counts -> bbase ----
__global__ __launch_bounds__(1024) void bscan_kernel(const int* __restrict__ cursor,
    int* __restrict__ bbase, int* __restrict__ row_ptr, int NBK, int N) {
    __shared__ int ls[1024];
    int t = threadIdx.x;
    int v = (t < NBK) ? min(cursor[t], CAP) : 0;
    ls[t] = v;
    __syncthreads();
    for (int off = 1; off < 1024; off <<= 1) {
        int xv = (t >= off) ? ls[t - off] : 0;
        __syncthreads();
        ls[t] += xv;
        __syncthreads();
    }
    if (t < NBK) bbase[t] = ls[t] - v;
    if (t == NBK - 1) row_ptr[N] = ls[t];
}

// ---- per-bucket counting sort: row_ptr, deg->dis, sx4, coalesced col ----
__global__ __launch_bounds__(256) void csr_sort_kernel(const unsigned* __restrict__ colb,
    const int* __restrict__ cursor, const int* __restrict__ bbase,
    const float* __restrict__ x, int* __restrict__ row_ptr, int* __restrict__ col,
    float* __restrict__ dis, float4* __restrict__ sx4, int N) {
    __shared__ unsigned ebuf[CAP];
    __shared__ int sbuf[CAP];
    __shared__ int cnt[SPAN], pref[SPAN], fill[SPAN];
    int b = blockIdx.x, tid = threadIdx.x;
    int n = min(cursor[b], CAP);
    int base = b * CAP, bb = bbase[b];
    if (tid < SPAN) cnt[tid] = 0;
    for (int i = tid; i < n; i += 256) ebuf[i] = colb[base + i];
    __syncthreads();
    for (int i = tid; i < n; i += 256) atomicAdd(&cnt[(ebuf[i] >> 17) & 127], 1);
    __syncthreads();
    if (tid < SPAN) pref[tid] = cnt[tid];
    __syncthreads();
    for (int off = 1; off < SPAN; off <<= 1) {
        int xv = (tid < SPAN && tid >= off) ? pref[tid - off] : 0;
        __syncthreads();
        if (tid < SPAN) pref[tid] += xv;
        __syncthreads();
    }
    if (tid < SPAN) {
        int ex = pref[tid] - cnt[tid];
        fill[tid] = ex;
        int node = b * SPAN + tid;
        if (node < N) {
            row_ptr[node] = bb + ex;
            float r = rsqrtf((float)(cnt[tid] + 1));
            dis[node] = r;
            float4 q;
            q.x = r * x[node * 3 + 0];
            q.y = r * x[node * 3 + 1];
            q.z = r * x[node * 3 + 2];
            q.w = 0.f;
            sx4[node] = q;
        }
    }
    __syncthreads();
    for (int i = tid; i < n; i += 256) {
        unsigned e = ebuf[i];
        int pos = atomicAdd(&fill[(e >> 17) & 127], 1);
        sbuf[pos] = (int)(e & 0x1FFFF);
    }
    __syncthreads();
    for (int i = tid; i < n; i += 256) col[bb + i] = sbuf[i];
}

// ---- layer 1: aggregate sx (float4) + W1 + bias + elu; s1h = fp16(dis*h1) ----
__global__ void agg3_kernel(const float4* __restrict__ sx4, const int* __restrict__ row_ptr,
                            const int* __restrict__ col, const float* __restrict__ dis,
                            const float* __restrict__ W1, const float* __restrict__ b1,
                            __half* __restrict__ s1h, int N) {
    int wave = (blockIdx.x * blockDim.x + threadIdx.x) >> 6;
    int lane = threadIdx.x & 63;
    if (wave >= N) return;
    int d = wave;
    int start = row_ptr[d], end = row_ptr[d + 1];
    float a0 = 0.f, a1 = 0.f, a2v = 0.f;
    for (int i = start + lane; i < end; i += 64) {
        float4 q = sx4[col[i]];
        a0 += q.x; a1 += q.y; a2v += q.z;
    }
#pragma unroll
    for (int off = 32; off; off >>= 1) {
        a0  += __shfl_xor(a0, off);
        a1  += __shfl_xor(a1, off);
        a2v += __shfl_xor(a2v, off);
    }
    float4 qd = sx4[d];   // self loop
    a0 += qd.x; a1 += qd.y; a2v += qd.z;
    float r = dis[d];
    float v = r * (a0 * W1[lane] + a1 * W1[64 + lane] + a2v * W1[128 + lane]) + b1[lane];
    s1h[(size_t)d * 64 + lane] = __float2half(r * elu(v));
}

// ---- layer 2: 2 nodes/wave, half2 gathers (128 B/row), fp32 accum ----
__global__ void agg64_kernel(const __half2* __restrict__ s1h, const int* __restrict__ row_ptr,
                             const int* __restrict__ col, const float* __restrict__ dis,
                             float* __restrict__ a2, int N) {
    int wave = (blockIdx.x * blockDim.x + threadIdx.x) >> 6;
    int lane = threadIdx.x & 63;
    int hl = lane & 31;
    int d = wave * 2 + (lane >> 5);
    bool act = d < N;
    int start = 0, end = 0;
    if (act) { start = row_ptr[d]; end = row_ptr[d + 1]; }
    float a0x = 0.f, a0y = 0.f, a1x = 0.f, a1y = 0.f;
    float a2x = 0.f, a2y = 0.f, a3x = 0.f, a3y = 0.f;
    float a4x = 0.f, a4y = 0.f, a5x = 0.f, a5y = 0.f;
    float a6x = 0.f, a6y = 0.f, a7x = 0.f, a7y = 0.f;
    if (act) {   // self loop
        float2 v = __half22float2(s1h[(size_t)d * 32 + hl]);
        a0x = v.x; a0y = v.y;
    }
    int i = start;
    for (; i + 7 < end; i += 8) {
        int c0 = col[i],     c1 = col[i + 1], c2 = col[i + 2], c3 = col[i + 3];
        int c4 = col[i + 4], c5 = col[i + 5], c6 = col[i + 6], c7 = col[i + 7];
        float2 v0 = __half22float2(s1h[(size_t)c0 * 32 + hl]);
        float2 v1 = __half22float2(s1h[(size_t)c1 * 32 + hl]);
        float2 v2 = __half22float2(s1h[(size_t)c2 * 32 + hl]);
        float2 v3 = __half22float2(s1h[(size_t)c3 * 32 + hl]);
        float2 v4 = __half22float2(s1h[(size_t)c4 * 32 + hl]);
        float2 v5 = __half22float2(s1h[(size_t)c5 * 32 + hl]);
        float2 v6 = __half22float2(s1h[(size_t)c6 * 32 + hl]);
        float2 v7 = __half22float2(s1h[(size_t)c7 * 32 + hl]);
        a0x += v0.x; a0y += v0.y; a1x += v1.x; a1y += v1.y;
        a2x += v2.x; a2y += v2.y; a3x += v3.x; a3y += v3.y;
        a4x += v4.x; a4y += v4.y; a5x += v5.x; a5y += v5.y;
        a6x += v6.x; a6y += v6.y; a7x += v7.x; a7y += v7.y;
    }
    for (; i < end; ++i) {
        float2 v = __half22float2(s1h[(size_t)col[i] * 32 + hl]);
        a0x += v.x; a0y += v.y;
    }
    if (act) {
        float r = dis[d];
        float2 o;
        o.x = r * (((a0x + a1x) + (a2x + a3x)) + ((a4x + a5x) + (a6x + a7x)));
        o.y = r * (((a0y + a1y) + (a2y + a3y)) + ((a4y + a5y) + (a6y + a7y)));
        *(float2*)(a2 + (size_t)d * 64 + 2 * hl) = o;
    }
}

// ---- h1: mt = elu(elu(a2@W2+b2)@Wm1+bm1)^T in FP16 [j][node] ----
// LDS = tt only (33 KB) -> 4 blocks/CU. W2 & Wm1 read from global (L1-hot).
// Stage A: 8f x 4n regs. Stage B: 8j x 8n regs, Wm1 global b128, tt LDS b128.
__global__ __launch_bounds__(256, 4) void h1_kernel(const float* __restrict__ a2,
    const float* __restrict__ W2g, const float* __restrict__ b2g,
    const float* __restrict__ Wm1g, const float* __restrict__ bm1g,
    __half* __restrict__ mt, int N) {
    __shared__ float tt[64 * 128];     // [f][n] 32 KB
    __shared__ float b2s[64];
    __shared__ float bm1s[128];
    int tid = threadIdx.x;
    if (tid < 64)  b2s[tid]  = b2g[tid];
    if (tid < 128) bm1s[tid] = bm1g[tid];
    __syncthreads();

    int base = blockIdx.x * 128;
    // ---- stage A: acc[8f][4n] over k=0..63; a2 & W2 from global (L1) ----
    {
        int fA = (tid & 7) * 8;
        int nA = (tid >> 3) * 4;
        float acc[8][4];
#pragma unroll
        for (int f = 0; f < 8; ++f) {
            float bb = b2s[fA + f];
#pragma unroll
            for (int i = 0; i < 4; ++i) acc[f][i] = bb;
        }
        const float* ar0 = a2 + (size_t)min(base + nA + 0, N - 1) * 64;
        const float* ar1 = a2 + (size_t)min(base + nA + 1, N - 1) * 64;
        const float* ar2 = a2 + (size_t)min(base + nA + 2, N - 1) * 64;
        const float* ar3 = a2 + (size_t)min(base + nA + 3, N - 1) * 64;
#pragma unroll 4
        for (int k = 0; k < 64; k += 4) {
            float4 q0 = *(const float4*)(ar0 + k);
            float4 q1 = *(const float4*)(ar1 + k);
            float4 q2 = *(const float4*)(ar2 + k);
            float4 q3 = *(const float4*)(ar3 + k);
            float av0[4] = {q0.x, q0.y, q0.z, q0.w};
            float av1[4] = {q1.x, q1.y, q1.z, q1.w};
            float av2[4] = {q2.x, q2.y, q2.z, q2.w};
            float av3[4] = {q3.x, q3.y, q3.z, q3.w};
#pragma unroll
            for (int kk = 0; kk < 4; ++kk) {
                float4 wlo = *(const float4*)(W2g + (k + kk) * 64 + fA);
                float4 whi = *(const float4*)(W2g + (k + kk) * 64 + fA + 4);
                float wv[8] = {wlo.x, wlo.y, wlo.z, wlo.w, whi.x, whi.y, whi.z, whi.w};
#pragma unroll
                for (int f = 0; f < 8; ++f) {
                    acc[f][0] = fmaf(wv[f], av0[kk], acc[f][0]);
                    acc[f][1] = fmaf(wv[f], av1[kk], acc[f][1]);
                    acc[f][2] = fmaf(wv[f], av2[kk], acc[f][2]);
                    acc[f][3] = fmaf(wv[f], av3[kk], acc[f][3]);
                }
            }
        }
#pragma unroll
        for (int f = 0; f < 8; ++f) {
            float4 v;
            v.x = elu(acc[f][0]); v.y = elu(acc[f][1]);
            v.z = elu(acc[f][2]); v.w = elu(acc[f][3]);
            *(float4*)(tt + (fA + f) * 128 + nA) = v;
        }
    }
    __syncthreads();
    // ---- stage B: accB[8j][8n] over f=0..63; Wm1 global b128, tt LDS b128 ----
    {
        int jB = (tid & 15) * 8;
        int nB = (tid >> 4) * 8;
        float accB[8][8];
#pragma unroll
        for (int j = 0; j < 8; ++j) {
            float bb = bm1s[jB + j];
#pragma unroll
            for (int i = 0; i < 8; ++i) accB[j][i] = bb;
        }
#pragma unroll 4
        for (int f = 0; f < 64; ++f) {
            float4 w0 = *(const float4*)(Wm1g + f * 128 + jB);
            float4 w1 = *(const float4*)(Wm1g + f * 128 + jB + 4);
            float4 t0 = *(const float4*)(tt + f * 128 + nB);
            float4 t1 = *(const float4*)(tt + f * 128 + nB + 4);
            float wv[8] = {w0.x, w0.y, w0.z, w0.w, w1.x, w1.y, w1.z, w1.w};
            float tv[8] = {t0.x, t0.y, t0.z, t0.w, t1.x, t1.y, t1.z, t1.w};
#pragma unroll
            for (int j = 0; j < 8; ++j)
#pragma unroll
                for (int i = 0; i < 8; ++i)
                    accB[j][i] = fmaf(wv[j], tv[i], accB[j][i]);
        }
        // write mt[j][node] fp16, 16B per j-row (8 nodes)
        if (base + 128 <= N) {
#pragma unroll
            for (int j = 0; j < 8; ++j) {
                __half2 h[4];
#pragma unroll
                for (int p = 0; p < 4; ++p)
                    h[p] = __floats2half2_rn(elu(accB[j][2 * p]), elu(accB[j][2 * p + 1]));
                *(float4*)(mt + (size_t)(jB + j) * N + base + nB) = *(float4*)h;
            }
        } else {
#pragma unroll
            for (int j = 0; j < 8; ++j)
#pragma unroll
                for (int i = 0; i < 8; ++i) {
                    int node = base + nB + i;
                    if (node < N)
                        mt[(size_t)(jB + j) * N + node] = __float2half(elu(accB[j][i]));
                }
        }
    }
}

// ---- h2: out = softmax(mt^T @ Wm2 + bm2), thread per node ----
__global__ __launch_bounds__(256) void h2_kernel(const __half* __restrict__ mt,
    const float* __restrict__ Wm2g, const float* __restrict__ bm2g,
    float* __restrict__ out, int N) {
    __shared__ float Wt[15 * 128];   // transposed [c][j]
    int tid = threadIdx.x;
    for (int i = tid; i < 15 * 128; i += 256) {
        int c = i >> 7, j = i & 127;
        Wt[i] = Wm2g[j * 15 + c];
    }
    __syncthreads();
    int node = blockIdx.x * 256 + tid;
    if (node >= N) return;
    float lg[15];
#pragma unroll
    for (int c = 0; c < 15; ++c) lg[c] = bm2g[c];
#pragma unroll 4
    for (int j4 = 0; j4 < 128; j4 += 4) {
        float m0 = __half2float(mt[(size_t)(j4 + 0) * N + node]);
        float m1 = __half2float(mt[(size_t)(j4 + 1) * N + node]);
        float m2 = __half2float(mt[(size_t)(j4 + 2) * N + node]);
        float m3 = __half2float(mt[(size_t)(j4 + 3) * N + node]);
#pragma unroll
        for (int c = 0; c < 15; ++c) {
            float4 w = *(const float4*)(Wt + c * 128 + j4);
            lg[c] = fmaf(m0, w.x, fmaf(m1, w.y, fmaf(m2, w.z, fmaf(m3, w.w, lg[c]))));
        }
    }
    float mx = lg[0];
#pragma unroll
    for (int c = 1; c < 15; ++c) mx = fmaxf(mx, lg[c]);
    float ex[15], s = 0.f;
#pragma unroll
    for (int c = 0; c < 15; ++c) { ex[c] = __expf(lg[c] - mx); s += ex[c]; }
    float inv = 1.f / s;
#pragma unroll
    for (int c = 0; c < 15; ++c) out[(size_t)node * 15 + c] = ex[c] * inv;
}

extern "C" void kernel_launch(void* const* d_in, const int* in_sizes, int n_in,
                              void* d_out, int out_size, void* d_ws, size_t ws_size,
                              hipStream_t stream) {
    const float* x   = (const float*)d_in[0];
    const int*   ei  = (const int*)d_in[1];
    const float* W1  = (const float*)d_in[2];
    const float* b1  = (const float*)d_in[3];
    const float* W2  = (const float*)d_in[4];
    const float* b2  = (const float*)d_in[5];
    const float* Wm1 = (const float*)d_in[6];
    const float* bm1 = (const float*)d_in[7];
    const float* Wm2 = (const float*)d_in[8];
    const float* bm2 = (const float*)d_in[9];
    float* out = (float*)d_out;

    int N = in_sizes[0] / 3;
    int E = in_sizes[1] / 2;
    const int* src = ei;
    const int* dst = ei + E;
    int NBK = (N + SPAN - 1) / SPAN;   // 782

    uintptr_t p = (uintptr_t)d_ws;
    auto carve = [&](size_t bytes) -> void* {
        p = (p + 255) & ~(uintptr_t)255;
        void* r = (void*)p;
        p += bytes;
        return r;
    };
    float*    a2      = (float*)carve((size_t)N * 64 * 4);   // colb aliases this
    int*      cursor  = (int*)carve((size_t)NBK * 4);
    int*      bbase   = (int*)carve((size_t)NBK * 4);
    int*      row_ptr = (int*)carve((size_t)(N + 1) * 4);
    float*    dis     = (float*)carve((size_t)N * 4);
    float4*   sx4     = (float4*)carve((size_t)N * 16);
    int*      col     = (int*)carve((size_t)E * 4);
    __half*   s1h     = (__half*)carve((size_t)N * 64 * 2);
    __half*   mt      = (__half*)carve((size_t)N * 128 * 2);  // [128][N] fp16
    // colb (14.4 MB) aliases a2 (25.6 MB): dead after csr_sort; a2 written in agg64
    unsigned* colb = (unsigned*)a2;

    hipMemsetAsync(cursor, 0, (size_t)NBK * 4, stream);

    int nChunks = (E + CH - 1) / CH;
    int waveBlocks3  = (N + 3) / 4;   // agg3: 1 node/wave, 4 waves/block
    int waveBlocks64 = (N + 7) / 8;   // agg64: 2 nodes/wave, 4 waves/block
    int nTiles = (N + 127) / 128;
    scatter_kernel<<<nChunks, 256, 0, stream>>>(src, dst, cursor, colb, E, NBK, nChunks);
    bscan_kernel<<<1, 1024, 0, stream>>>(cursor, bbase, row_ptr, NBK, N);
    csr_sort_kernel<<<NBK, 256, 0, stream>>>(colb, cursor, bbase, x, row_ptr, col, dis, sx4, N);
    agg3_kernel<<<waveBlocks3, 256, 0, stream>>>(sx4, row_ptr, col, dis, W1, b1, s1h, N);
    agg64_kernel<<<waveBlocks64, 256, 0, stream>>>((const __half2*)s1h, row_ptr, col, dis, a2, N);
    h1_kernel<<<nTiles, 256, 0, stream>>>(a2, W2, b2, Wm1, bm1, mt, N);
    h2_kernel<<<(N + 255) / 256, 256, 0, stream>>>(mt, Wm2, bm2, out, N);
}